// Round 1
// baseline (491.825 us; speedup 1.0000x reference)
//
#include <hip/hip_runtime.h>
#include <math.h>

#define BB 16
#define NN 1024
#define MM 1024
#define DKK 512
#define CHUNKS 16

// scratch as device globals (fully rewritten every call; no ws_size assumption)
__device__ float g_u[BB*NN];
__device__ float g_v[BB*MM];
__device__ float g_w[BB*NN];        // row sums of perm (weights)
__device__ float g_wt[BB*3*NN];     // weighted_tgt
__device__ float g_pm[BB*CHUNKS*MM];
__device__ float g_ps[BB*CHUNKS*MM];

__global__ __launch_bounds__(256) void zero_v_kernel() {
    int i = blockIdx.x*256 + threadIdx.x;
    if (i < BB*MM) g_v[i] = 0.0f;
}

// C[b][i][j] = (sum_d A[b][d][i]*B[b][d][j]) / (sqrt(512)*temp[b])
__global__ __launch_bounds__(256) void gemm_scores(const float* __restrict__ A,
                                                   const float* __restrict__ Bm,
                                                   const float* __restrict__ temp,
                                                   float* __restrict__ C) {
    int b  = blockIdx.z;
    int i0 = blockIdx.y * 128;
    int j0 = blockIdx.x * 128;
    __shared__ float As[16][128];
    __shared__ float Bs[16][128];
    const float* Ab = A  + (size_t)b*DKK*NN;
    const float* Bb = Bm + (size_t)b*DKK*MM;
    int t  = threadIdx.x;
    int tx = t & 15, ty = t >> 4;
    float acc[8][8];
#pragma unroll
    for (int y=0;y<8;y++)
#pragma unroll
        for (int x=0;x<8;x++) acc[y][x]=0.0f;

    for (int d0=0; d0<DKK; d0+=16) {
#pragma unroll
        for (int r=0;r<8;r++){
            int idx = t + 256*r;
            int kk = idx >> 7, ii = idx & 127;
            As[kk][ii] = Ab[(size_t)(d0+kk)*NN + i0 + ii];
            Bs[kk][ii] = Bb[(size_t)(d0+kk)*MM + j0 + ii];
        }
        __syncthreads();
#pragma unroll
        for (int kk=0;kk<16;kk++){
            float av[8], bv[8];
#pragma unroll
            for (int r=0;r<8;r++){ av[r]=As[kk][ty*8+r]; bv[r]=Bs[kk][tx*8+r]; }
#pragma unroll
            for (int y=0;y<8;y++)
#pragma unroll
                for (int x=0;x<8;x++)
                    acc[y][x] = fmaf(av[y], bv[x], acc[y][x]);
        }
        __syncthreads();
    }
    float scale = 1.0f/(22.62741699796952f * temp[b]);
#pragma unroll
    for (int y=0;y<8;y++){
        int i = i0 + ty*8 + y;
        float4* Crow = (float4*)&C[((size_t)b*NN + i)*MM + j0 + tx*8];
        Crow[0] = make_float4(acc[y][0]*scale, acc[y][1]*scale, acc[y][2]*scale, acc[y][3]*scale);
        Crow[1] = make_float4(acc[y][4]*scale, acc[y][5]*scale, acc[y][6]*scale, acc[y][7]*scale);
    }
}

// u_i = lse_j({a_ij - v_j} U {0}), one wave per row
__global__ __launch_bounds__(256) void row_lse(const float* __restrict__ S) {
    int row  = blockIdx.x*4 + (threadIdx.x>>6);
    int lane = threadIdx.x & 63;
    int b = row >> 10;
    const float4* srow = (const float4*)(S + (size_t)row*MM);
    const float4* vb   = (const float4*)(g_v + (b<<10));
    float x[16];
#pragma unroll
    for (int k=0;k<4;k++){
        float4 s4 = srow[lane + 64*k];
        float4 v4 = vb[lane + 64*k];
        x[4*k+0]=s4.x-v4.x; x[4*k+1]=s4.y-v4.y; x[4*k+2]=s4.z-v4.z; x[4*k+3]=s4.w-v4.w;
    }
    float m = x[0];
#pragma unroll
    for (int k=1;k<16;k++) m = fmaxf(m, x[k]);
    float s = 0.0f;
#pragma unroll
    for (int k=0;k<16;k++) s += __expf(x[k]-m);
    for (int off=32; off; off>>=1){
        float om = __shfl_xor(m, off);
        float os = __shfl_xor(s, off);
        float nm = fmaxf(m, om);
        s = s*__expf(m-nm) + os*__expf(om-nm);
        m = nm;
    }
    // merge slack element {0}
    float nm = fmaxf(m, 0.0f);
    s = s*__expf(m-nm) + __expf(-nm);
    if (lane==0) g_u[row] = nm + __logf(s);
}

// partial col lse over a chunk of rows; 4 independent online chains for ILP
__global__ __launch_bounds__(256) void col_lse_partial(const float* __restrict__ S) {
    int b = blockIdx.z;
    int j = blockIdx.x*256 + threadIdx.x;
    int chunk = blockIdx.y;
    const int RC = NN/CHUNKS;     // 64
    int r0 = chunk*RC;
    const float* Sb = S + ((size_t)b*NN + r0)*MM;
    const float* ub = g_u + b*NN + r0;
    float m[4], s[4];
#pragma unroll
    for (int r=0;r<4;r++){ m[r]=-INFINITY; s[r]=0.0f; }
    for (int i=0;i<RC;i+=4){
#pragma unroll
        for (int r=0;r<4;r++){
            float x = Sb[(size_t)(i+r)*MM + j] - ub[i+r];
            float nm = fmaxf(m[r], x);
            s[r] = s[r]*__expf(m[r]-nm) + __expf(x-nm);
            m[r] = nm;
        }
    }
    float M = m[0], Ss = s[0];
#pragma unroll
    for (int r=1;r<4;r++){
        float nm = fmaxf(M, m[r]);
        Ss = Ss*__expf(M-nm) + s[r]*__expf(m[r]-nm);
        M = nm;
    }
    g_pm[(b*CHUNKS+chunk)*MM + j] = M;
    g_ps[(b*CHUNKS+chunk)*MM + j] = Ss;
}

__global__ __launch_bounds__(256) void col_lse_combine() {
    int idx = blockIdx.x*256 + threadIdx.x;   // 16384 columns total
    int b = idx >> 10; int j = idx & (MM-1);
    float m = -INFINITY, s = 0.0f;
    for (int c=0;c<CHUNKS;c++){
        float om = g_pm[(b*CHUNKS+c)*MM + j];
        float os = g_ps[(b*CHUNKS+c)*MM + j];
        float nm = fmaxf(m, om);
        s = s*__expf(m-nm) + os*__expf(om-nm);
        m = nm;
    }
    float nm = fmaxf(m, 0.0f);
    s = s*__expf(m-nm) + __expf(-nm);
    g_v[idx] = nm + __logf(s);
}

// perm_norm (in-place over S), row sums, and weighted_tgt; one wave per row
__global__ __launch_bounds__(256) void finalize_rows(float* __restrict__ S,
                                                     const float* __restrict__ tgt) {
    int row  = blockIdx.x*4 + (threadIdx.x>>6);
    int lane = threadIdx.x & 63;
    int b = row >> 10;
    int i = row & (NN-1);
    float ui = g_u[row];
    float4* srow = (float4*)(S + (size_t)row*MM);
    const float4* vb = (const float4*)(g_v + (b<<10));
    const float4* t0 = (const float4*)(tgt + (size_t)b*3*MM);
    const float4* t1 = (const float4*)(tgt + (size_t)b*3*MM + MM);
    const float4* t2 = (const float4*)(tgt + (size_t)b*3*MM + 2*MM);
    float p[16];
    float rs=0.f, a0=0.f, a1=0.f, a2=0.f;
#pragma unroll
    for (int k=0;k<4;k++){
        float4 s4 = srow[lane + 64*k];
        float4 v4 = vb[lane + 64*k];
        p[4*k+0] = __expf(s4.x - ui - v4.x);
        p[4*k+1] = __expf(s4.y - ui - v4.y);
        p[4*k+2] = __expf(s4.z - ui - v4.z);
        p[4*k+3] = __expf(s4.w - ui - v4.w);
        rs += p[4*k+0]+p[4*k+1]+p[4*k+2]+p[4*k+3];
        float4 w0 = t0[lane + 64*k];
        float4 w1 = t1[lane + 64*k];
        float4 w2 = t2[lane + 64*k];
        a0 += p[4*k+0]*w0.x + p[4*k+1]*w0.y + p[4*k+2]*w0.z + p[4*k+3]*w0.w;
        a1 += p[4*k+0]*w1.x + p[4*k+1]*w1.y + p[4*k+2]*w1.z + p[4*k+3]*w1.w;
        a2 += p[4*k+0]*w2.x + p[4*k+1]*w2.y + p[4*k+2]*w2.z + p[4*k+3]*w2.w;
    }
    for (int off=32; off; off>>=1){
        rs += __shfl_xor(rs, off);
        a0 += __shfl_xor(a0, off);
        a1 += __shfl_xor(a1, off);
        a2 += __shfl_xor(a2, off);
    }
    float inv = 1.0f/(rs + 1e-8f);
#pragma unroll
    for (int k=0;k<4;k++){
        srow[lane + 64*k] = make_float4(p[4*k+0]*inv, p[4*k+1]*inv, p[4*k+2]*inv, p[4*k+3]*inv);
    }
    if (lane==0){
        g_w[row] = rs;
        g_wt[(b*3+0)*NN + i] = a0*inv;
        g_wt[(b*3+1)*NN + i] = a1*inv;
        g_wt[(b*3+2)*NN + i] = a2*inv;
    }
}

// per-batch: weights_norm, centroids, H, 3x3 SVD (Jacobi on H^T H, fp64), R, t
__global__ __launch_bounds__(256) void procrustes(const float* __restrict__ src,
                                                  float* __restrict__ out) {
    int b = blockIdx.x;
    int t = threadIdx.x;
    __shared__ float red[256];
    auto bsum = [&](float v)->float{
        red[t]=v; __syncthreads();
        for (int o=128;o>0;o>>=1){ if(t<o) red[t]+=red[t+o]; __syncthreads(); }
        float r=red[0]; __syncthreads(); return r;
    };
    const float* wrow = g_w + b*NN;
    float pw=0.f;
    for (int i=t;i<NN;i+=256) pw += wrow[i];
    float W = bsum(pw);
    float winv = 1.0f/(W + 1e-8f);
    const float* sb  = src  + (size_t)b*3*NN;
    const float* wtb = g_wt + (size_t)b*3*NN;
    float sc[3], tc[3];
    for (int c=0;c<3;c++){
        float p1=0.f,p2=0.f;
        for (int i=t;i<NN;i+=256){
            float wn = wrow[i]*winv;
            p1 += sb[c*NN+i]*wn;
            p2 += wtb[c*NN+i]*wn;
        }
        sc[c]=bsum(p1);
        tc[c]=bsum(p2);
    }
    float H[9];
    for (int c=0;c<3;c++)
        for (int d=0;d<3;d++){
            float p=0.f;
            for (int i=t;i<NN;i+=256){
                float wn = wrow[i]*winv;
                p += (sb[c*NN+i]-sc[c]) * ((wtb[d*NN+i]-tc[d])*wn);
            }
            H[c*3+d]=bsum(p);
        }
    if (t==0){
        double Hd[3][3];
        for (int r2=0;r2<3;r2++) for (int c2=0;c2<3;c2++) Hd[r2][c2]=H[r2*3+c2];
        // K = H^T H
        double K[3][3];
        for (int i2=0;i2<3;i2++)
            for (int j2=0;j2<3;j2++){
                double acc=0;
                for (int r2=0;r2<3;r2++) acc += Hd[r2][i2]*Hd[r2][j2];
                K[i2][j2]=acc;
            }
        double V[3][3]={{1,0,0},{0,1,0},{0,0,1}};
        const int PQ[3][2]={{0,1},{0,2},{1,2}};
        for (int sweep=0; sweep<30; ++sweep){
            double off = fabs(K[0][1])+fabs(K[0][2])+fabs(K[1][2]);
            if (off < 1e-26) break;
            for (int pi=0; pi<3; ++pi){
                int p = PQ[pi][0], q = PQ[pi][1];
                double apq = K[p][q];
                if (fabs(apq) < 1e-300) continue;
                double tau = (K[q][q]-K[p][p])/(2.0*apq);
                double tt  = (tau>=0.0?1.0:-1.0)/(fabs(tau)+sqrt(1.0+tau*tau));
                double c   = 1.0/sqrt(1.0+tt*tt);
                double s   = tt*c;
                double Kpp=K[p][p], Kqq=K[q][q];
                K[p][p] = Kpp - tt*apq;
                K[q][q] = Kqq + tt*apq;
                K[p][q] = 0.0; K[q][p] = 0.0;
                int r2 = 3-p-q;
                double Krp=K[r2][p], Krq=K[r2][q];
                K[r2][p] = c*Krp - s*Krq; K[p][r2]=K[r2][p];
                K[r2][q] = s*Krp + c*Krq; K[q][r2]=K[r2][q];
                for (int rr=0; rr<3; ++rr){
                    double vp=V[rr][p], vq=V[rr][q];
                    V[rr][p] = c*vp - s*vq;
                    V[rr][q] = s*vp + c*vq;
                }
            }
        }
        double lam[3]={K[0][0],K[1][1],K[2][2]};
        int o0=0,o1=1,o2=2,tmp;
        if (lam[o0]<lam[o1]){tmp=o0;o0=o1;o1=tmp;}
        if (lam[o0]<lam[o2]){tmp=o0;o0=o2;o2=tmp;}
        if (lam[o1]<lam[o2]){tmp=o1;o1=o2;o2=tmp;}
        int ord[3]={o0,o1,o2};
        double Vs[3][3], U[3][3];
        for (int k=0;k<3;k++)
            for (int r2=0;r2<3;r2++) Vs[r2][k]=V[r2][ord[k]];
        for (int k=0;k<3;k++){
            double ux = Hd[0][0]*Vs[0][k] + Hd[0][1]*Vs[1][k] + Hd[0][2]*Vs[2][k];
            double uy = Hd[1][0]*Vs[0][k] + Hd[1][1]*Vs[1][k] + Hd[1][2]*Vs[2][k];
            double uz = Hd[2][0]*Vs[0][k] + Hd[2][1]*Vs[1][k] + Hd[2][2]*Vs[2][k];
            double n = sqrt(ux*ux+uy*uy+uz*uz);
            if (n > 1e-30){ U[0][k]=ux/n; U[1][k]=uy/n; U[2][k]=uz/n; }
            else {
                // degenerate smallest singular value: complete with cross product
                double cx = U[1][0]*U[2][1]-U[2][0]*U[1][1];
                double cy = U[2][0]*U[0][1]-U[0][0]*U[2][1];
                double cz = U[0][0]*U[1][1]-U[1][0]*U[0][1];
                U[0][k]=cx; U[1][k]=cy; U[2][k]=cz;
            }
        }
        // r = Vs * U^T, det
        double rm[3][3];
        for (int i2=0;i2<3;i2++)
            for (int j2=0;j2<3;j2++)
                rm[i2][j2] = Vs[i2][0]*U[j2][0] + Vs[i2][1]*U[j2][1] + Vs[i2][2]*U[j2][2];
        double det = rm[0][0]*(rm[1][1]*rm[2][2]-rm[1][2]*rm[2][1])
                   - rm[0][1]*(rm[1][0]*rm[2][2]-rm[1][2]*rm[2][0])
                   + rm[0][2]*(rm[1][0]*rm[2][1]-rm[1][1]*rm[2][0]);
        double R[3][3];
        for (int i2=0;i2<3;i2++)
            for (int j2=0;j2<3;j2++)
                R[i2][j2] = Vs[i2][0]*U[j2][0] + Vs[i2][1]*U[j2][1] + det*Vs[i2][2]*U[j2][2];
        double tv[3];
        for (int i2=0;i2<3;i2++)
            tv[i2] = -(R[i2][0]*sc[0]+R[i2][1]*sc[1]+R[i2][2]*sc[2]) + tc[i2];
        for (int i2=0;i2<3;i2++)
            for (int j2=0;j2<3;j2++)
                out[b*9 + i2*3 + j2] = (float)R[i2][j2];
        for (int i2=0;i2<3;i2++)
            out[144 + b*3 + i2] = (float)tv[i2];
    }
}

extern "C" void kernel_launch(void* const* d_in, const int* in_sizes, int n_in,
                              void* d_out, int out_size, void* d_ws, size_t ws_size,
                              hipStream_t stream) {
    const float* src_emb = (const float*)d_in[0];
    const float* tgt_emb = (const float*)d_in[1];
    const float* src     = (const float*)d_in[2];
    const float* tgt     = (const float*)d_in[3];
    const float* temp    = (const float*)d_in[4];
    float* out = (float*)d_out;
    float* S = out + 192;   // perm_norm region doubles as scores buffer

    hipLaunchKernelGGL(zero_v_kernel, dim3(64), dim3(256), 0, stream);
    hipLaunchKernelGGL(gemm_scores, dim3(8,8,16), dim3(256), 0, stream,
                       src_emb, tgt_emb, temp, S);
    for (int it=0; it<5; ++it){
        hipLaunchKernelGGL(row_lse, dim3(4096), dim3(256), 0, stream, S);
        hipLaunchKernelGGL(col_lse_partial, dim3(4,CHUNKS,16), dim3(256), 0, stream, S);
        hipLaunchKernelGGL(col_lse_combine, dim3(64), dim3(256), 0, stream);
    }
    hipLaunchKernelGGL(finalize_rows, dim3(4096), dim3(256), 0, stream, S, tgt);
    hipLaunchKernelGGL(procrustes, dim3(16), dim3(256), 0, stream, src, out);
}

// Round 3
// 408.062 us; speedup vs baseline: 1.2053x; 1.2053x over previous
//
#include <hip/hip_runtime.h>
#include <math.h>

#define BB 16
#define NN 1024
#define MM 1024
#define DKK 512
#define CHUNKS 16

typedef short short8 __attribute__((ext_vector_type(8)));
typedef float f32x4 __attribute__((ext_vector_type(4)));

// scratch as device globals (fully rewritten every call)
__device__ float g_u[BB*NN];
__device__ float g_v[BB*MM];
__device__ float g_w[BB*NN];
__device__ float g_wt[BB*3*NN];
__device__ float g_pm[BB*CHUNKS*MM];
__device__ float g_ps[BB*CHUNKS*MM];
// split-bf16 operands, [B][N][DK] k-contiguous; 16B-aligned for uint4 access
__device__ __attribute__((aligned(16))) unsigned short gAh[BB*NN*DKK];
__device__ __attribute__((aligned(16))) unsigned short gAl[BB*NN*DKK];
__device__ __attribute__((aligned(16))) unsigned short gBh[BB*MM*DKK];
__device__ __attribute__((aligned(16))) unsigned short gBl[BB*MM*DKK];

__global__ __launch_bounds__(256) void zero_v_kernel() {
    int i = blockIdx.x*256 + threadIdx.x;
    if (i < BB*MM) g_v[i] = 0.0f;
}

__device__ __forceinline__ unsigned int bf16_rne(float x){
    unsigned int u = __float_as_uint(x);
    return (u + 0x7fffu + ((u>>16)&1u)) >> 16;
}

// X [16][512][1024] fp32 -> (which? gB : gA) hi/lo [16][1024][512] bf16, transposed.
// NOTE: destination selected INSIDE device code — __device__ globals must not be
// passed as kernel args from host (host shadow address -> GPU page fault).
__global__ __launch_bounds__(256) void convert_split(const float* __restrict__ X,
                                                     int which) {
    unsigned short* Hh = which ? gBh : gAh;
    unsigned short* Hl = which ? gBl : gAl;
    int b  = blockIdx.z;
    int d0 = blockIdx.y * 64;
    int i0 = blockIdx.x * 64;
    __shared__ float T[64*65];
    const float* Xb = X + ((size_t)b*DKK + d0)*NN + i0;
    int t = threadIdx.x;
#pragma unroll
    for (int it=0; it<4; ++it){
        int lin = t + 256*it;          // 0..1023
        int d = lin >> 4;              // 0..63
        int i4 = lin & 15;
        float4 v = *(const float4*)(Xb + (size_t)d*NN + i4*4);
        T[(i4*4+0)*65 + d] = v.x;
        T[(i4*4+1)*65 + d] = v.y;
        T[(i4*4+2)*65 + d] = v.z;
        T[(i4*4+3)*65 + d] = v.w;
    }
    __syncthreads();
    size_t obase = ((size_t)b*NN + i0)*DKK + d0;
#pragma unroll
    for (int it=0; it<2; ++it){
        int c = t + 256*it;            // 0..511
        int i = c >> 3;
        int p = c & 7;
        unsigned int hw[4], lw[4];
#pragma unroll
        for (int j=0;j<4;j++){
            float x0 = T[i*65 + p*8 + 2*j];
            float x1 = T[i*65 + p*8 + 2*j+1];
            unsigned int h0 = bf16_rne(x0);
            unsigned int h1 = bf16_rne(x1);
            float hf0 = __uint_as_float(h0<<16);
            float hf1 = __uint_as_float(h1<<16);
            unsigned int l0 = bf16_rne(x0 - hf0);
            unsigned int l1 = bf16_rne(x1 - hf1);
            hw[j] = h0 | (h1<<16);
            lw[j] = l0 | (l1<<16);
        }
        size_t eo = obase + (size_t)i*DKK + p*8;
        uint4 hv; hv.x=hw[0]; hv.y=hw[1]; hv.z=hw[2]; hv.w=hw[3];
        uint4 lv; lv.x=lw[0]; lv.y=lw[1]; lv.z=lw[2]; lv.w=lw[3];
        *(uint4*)(Hh + eo) = hv;
        *(uint4*)(Hl + eo) = lv;
    }
}

// C[b][i][j] = (sum_d A[d][i]*B[d][j]) / (sqrt(512)*temp[b]) via split-bf16 MFMA
__global__ __launch_bounds__(256) void gemm_mfma(const float* __restrict__ temp,
                                                 float* __restrict__ C) {
    int b  = blockIdx.z;
    int i0 = blockIdx.y * 128;
    int j0 = blockIdx.x * 128;
    __shared__ __attribute__((aligned(16))) char lds[40960]; // Ah,Al,Bh,Bl tiles; 128 rows x 80B each half
    int t = threadIdx.x;
    int lane = t & 63, w = t >> 6;
    int wr = w >> 1, wc = w & 1;
    const size_t eb = (size_t)b * NN * DKK;
    const uint4* pAh = (const uint4*)(gAh + eb);
    const uint4* pAl = (const uint4*)(gAl + eb);
    const uint4* pBh = (const uint4*)(gBh + eb);
    const uint4* pBl = (const uint4*)(gBl + eb);
    int rr = t >> 2, pp = t & 3;   // staging: row 0..63, 16B-chunk pos 0..3

    f32x4 acc[16];
#pragma unroll
    for (int q=0;q<16;q++) acc[q] = (f32x4){0.f,0.f,0.f,0.f};

    uint4 ra0, ra1, la0, la1, rb0, rb1, lb0, lb1;
    auto loadk = [&](int k0){
        int kq = k0 >> 3;   // uint4 index within a 64-uint4 row
        ra0 = pAh[(size_t)(i0+rr)*64 + kq + pp];
        ra1 = pAh[(size_t)(i0+rr+64)*64 + kq + pp];
        la0 = pAl[(size_t)(i0+rr)*64 + kq + pp];
        la1 = pAl[(size_t)(i0+rr+64)*64 + kq + pp];
        rb0 = pBh[(size_t)(j0+rr)*64 + kq + pp];
        rb1 = pBh[(size_t)(j0+rr+64)*64 + kq + pp];
        lb0 = pBl[(size_t)(j0+rr)*64 + kq + pp];
        lb1 = pBl[(size_t)(j0+rr+64)*64 + kq + pp];
    };
    loadk(0);

    const char* fa = lds + (wr*64 + (lane&15))*80 + (lane>>4)*16;
    const char* fb = lds + 20480 + (wc*64 + (lane&15))*80 + (lane>>4)*16;
    char* wbase = lds + rr*80 + pp*16;

    for (int ks=0; ks<16; ++ks){
        __syncthreads();
        *(uint4*)(wbase + 0)     = ra0;
        *(uint4*)(wbase + 5120)  = ra1;
        *(uint4*)(wbase + 10240) = la0;
        *(uint4*)(wbase + 15360) = la1;
        *(uint4*)(wbase + 20480) = rb0;
        *(uint4*)(wbase + 25600) = rb1;
        *(uint4*)(wbase + 30720) = lb0;
        *(uint4*)(wbase + 35840) = lb1;
        __syncthreads();
        if (ks+1 < 16) loadk((ks+1)*32);

        short8 ah[4], al[4];
#pragma unroll
        for (int mf=0;mf<4;mf++){
            ah[mf] = *(const short8*)(fa + mf*1280);
            al[mf] = *(const short8*)(fa + 10240 + mf*1280);
        }
#pragma unroll
        for (int nf=0;nf<4;nf++){
            short8 bh = *(const short8*)(fb + nf*1280);
            short8 bl = *(const short8*)(fb + 10240 + nf*1280);
#pragma unroll
            for (int mf=0;mf<4;mf++){
                acc[mf*4+nf] = __builtin_amdgcn_mfma_f32_16x16x32_bf16(ah[mf], bh, acc[mf*4+nf], 0,0,0);
                acc[mf*4+nf] = __builtin_amdgcn_mfma_f32_16x16x32_bf16(ah[mf], bl, acc[mf*4+nf], 0,0,0);
                acc[mf*4+nf] = __builtin_amdgcn_mfma_f32_16x16x32_bf16(al[mf], bh, acc[mf*4+nf], 0,0,0);
            }
        }
    }

    float scale = 1.0f/(22.62741699796952f * temp[b]);
    float* Cb = C + ((size_t)b<<20);
    int r0c = i0 + wr*64 + ((lane>>4)<<2);
    int c0c = j0 + wc*64 + (lane&15);
#pragma unroll
    for (int mf=0;mf<4;mf++){
#pragma unroll
        for (int r2=0;r2<4;r2++){
            float* rowp = Cb + (size_t)(r0c + mf*16 + r2)*MM + c0c;
#pragma unroll
            for (int nf=0;nf<4;nf++)
                rowp[nf*16] = acc[mf*4+nf][r2]*scale;
        }
    }
}

// u_i = lse_j({a_ij - v_j} U {0}), one wave per row
__global__ __launch_bounds__(256) void row_lse(const float* __restrict__ S) {
    int row  = blockIdx.x*4 + (threadIdx.x>>6);
    int lane = threadIdx.x & 63;
    int b = row >> 10;
    const float4* srow = (const float4*)(S + (size_t)row*MM);
    const float4* vb   = (const float4*)(g_v + (b<<10));
    float x[16];
#pragma unroll
    for (int k=0;k<4;k++){
        float4 s4 = srow[lane + 64*k];
        float4 v4 = vb[lane + 64*k];
        x[4*k+0]=s4.x-v4.x; x[4*k+1]=s4.y-v4.y; x[4*k+2]=s4.z-v4.z; x[4*k+3]=s4.w-v4.w;
    }
    float m = x[0];
#pragma unroll
    for (int k=1;k<16;k++) m = fmaxf(m, x[k]);
    float s = 0.0f;
#pragma unroll
    for (int k=0;k<16;k++) s += __expf(x[k]-m);
    for (int off=32; off; off>>=1){
        float om = __shfl_xor(m, off);
        float os = __shfl_xor(s, off);
        float nm = fmaxf(m, om);
        s = s*__expf(m-nm) + os*__expf(om-nm);
        m = nm;
    }
    float nm = fmaxf(m, 0.0f);
    s = s*__expf(m-nm) + __expf(-nm);
    if (lane==0) g_u[row] = nm + __logf(s);
}

__global__ __launch_bounds__(256) void col_lse_partial(const float* __restrict__ S) {
    int b = blockIdx.z;
    int j = blockIdx.x*256 + threadIdx.x;
    int chunk = blockIdx.y;
    const int RC = NN/CHUNKS;
    int r0 = chunk*RC;
    const float* Sb = S + ((size_t)b*NN + r0)*MM;
    const float* ub = g_u + b*NN + r0;
    float m[4], s[4];
#pragma unroll
    for (int r=0;r<4;r++){ m[r]=-INFINITY; s[r]=0.0f; }
    for (int i=0;i<RC;i+=4){
#pragma unroll
        for (int r=0;r<4;r++){
            float x = Sb[(size_t)(i+r)*MM + j] - ub[i+r];
            float nm = fmaxf(m[r], x);
            s[r] = s[r]*__expf(m[r]-nm) + __expf(x-nm);
            m[r] = nm;
        }
    }
    float M = m[0], Ss = s[0];
#pragma unroll
    for (int r=1;r<4;r++){
        float nm = fmaxf(M, m[r]);
        Ss = Ss*__expf(M-nm) + s[r]*__expf(m[r]-nm);
        M = nm;
    }
    g_pm[(b*CHUNKS+chunk)*MM + j] = M;
    g_ps[(b*CHUNKS+chunk)*MM + j] = Ss;
}

__global__ __launch_bounds__(256) void col_lse_combine() {
    int idx = blockIdx.x*256 + threadIdx.x;
    int b = idx >> 10; int j = idx & (MM-1);
    float m = -INFINITY, s = 0.0f;
    for (int c=0;c<CHUNKS;c++){
        float om = g_pm[(b*CHUNKS+c)*MM + j];
        float os = g_ps[(b*CHUNKS+c)*MM + j];
        float nm = fmaxf(m, om);
        s = s*__expf(m-nm) + os*__expf(om-nm);
        m = nm;
    }
    float nm = fmaxf(m, 0.0f);
    s = s*__expf(m-nm) + __expf(-nm);
    g_v[idx] = nm + __logf(s);
}

__global__ __launch_bounds__(256) void finalize_rows(float* __restrict__ S,
                                                     const float* __restrict__ tgt) {
    int row  = blockIdx.x*4 + (threadIdx.x>>6);
    int lane = threadIdx.x & 63;
    int b = row >> 10;
    int i = row & (NN-1);
    float ui = g_u[row];
    float4* srow = (float4*)(S + (size_t)row*MM);
    const float4* vb = (const float4*)(g_v + (b<<10));
    const float4* t0 = (const float4*)(tgt + (size_t)b*3*MM);
    const float4* t1 = (const float4*)(tgt + (size_t)b*3*MM + MM);
    const float4* t2 = (const float4*)(tgt + (size_t)b*3*MM + 2*MM);
    float p[16];
    float rs=0.f, a0=0.f, a1=0.f, a2=0.f;
#pragma unroll
    for (int k=0;k<4;k++){
        float4 s4 = srow[lane + 64*k];
        float4 v4 = vb[lane + 64*k];
        p[4*k+0] = __expf(s4.x - ui - v4.x);
        p[4*k+1] = __expf(s4.y - ui - v4.y);
        p[4*k+2] = __expf(s4.z - ui - v4.z);
        p[4*k+3] = __expf(s4.w - ui - v4.w);
        rs += p[4*k+0]+p[4*k+1]+p[4*k+2]+p[4*k+3];
        float4 w0 = t0[lane + 64*k];
        float4 w1 = t1[lane + 64*k];
        float4 w2 = t2[lane + 64*k];
        a0 += p[4*k+0]*w0.x + p[4*k+1]*w0.y + p[4*k+2]*w0.z + p[4*k+3]*w0.w;
        a1 += p[4*k+0]*w1.x + p[4*k+1]*w1.y + p[4*k+2]*w1.z + p[4*k+3]*w1.w;
        a2 += p[4*k+0]*w2.x + p[4*k+1]*w2.y + p[4*k+2]*w2.z + p[4*k+3]*w2.w;
    }
    for (int off=32; off; off>>=1){
        rs += __shfl_xor(rs, off);
        a0 += __shfl_xor(a0, off);
        a1 += __shfl_xor(a1, off);
        a2 += __shfl_xor(a2, off);
    }
    float inv = 1.0f/(rs + 1e-8f);
#pragma unroll
    for (int k=0;k<4;k++){
        srow[lane + 64*k] = make_float4(p[4*k+0]*inv, p[4*k+1]*inv, p[4*k+2]*inv, p[4*k+3]*inv);
    }
    if (lane==0){
        g_w[row] = rs;
        g_wt[(b*3+0)*NN + i] = a0*inv;
        g_wt[(b*3+1)*NN + i] = a1*inv;
        g_wt[(b*3+2)*NN + i] = a2*inv;
    }
}

__global__ __launch_bounds__(256) void procrustes(const float* __restrict__ src,
                                                  float* __restrict__ out) {
    int b = blockIdx.x;
    int t = threadIdx.x;
    __shared__ float red[256];
    auto bsum = [&](float v)->float{
        red[t]=v; __syncthreads();
        for (int o=128;o>0;o>>=1){ if(t<o) red[t]+=red[t+o]; __syncthreads(); }
        float r=red[0]; __syncthreads(); return r;
    };
    const float* wrow = g_w + b*NN;
    float pw=0.f;
    for (int i=t;i<NN;i+=256) pw += wrow[i];
    float W = bsum(pw);
    float winv = 1.0f/(W + 1e-8f);
    const float* sb  = src  + (size_t)b*3*NN;
    const float* wtb = g_wt + (size_t)b*3*NN;
    float sc[3], tc[3];
    for (int c=0;c<3;c++){
        float p1=0.f,p2=0.f;
        for (int i=t;i<NN;i+=256){
            float wn = wrow[i]*winv;
            p1 += sb[c*NN+i]*wn;
            p2 += wtb[c*NN+i]*wn;
        }
        sc[c]=bsum(p1);
        tc[c]=bsum(p2);
    }
    float H[9];
    for (int c=0;c<3;c++)
        for (int d=0;d<3;d++){
            float p=0.f;
            for (int i=t;i<NN;i+=256){
                float wn = wrow[i]*winv;
                p += (sb[c*NN+i]-sc[c]) * ((wtb[d*NN+i]-tc[d])*wn);
            }
            H[c*3+d]=bsum(p);
        }
    if (t==0){
        double Hd[3][3];
        for (int r2=0;r2<3;r2++) for (int c2=0;c2<3;c2++) Hd[r2][c2]=H[r2*3+c2];
        double K[3][3];
        for (int i2=0;i2<3;i2++)
            for (int j2=0;j2<3;j2++){
                double acc=0;
                for (int r2=0;r2<3;r2++) acc += Hd[r2][i2]*Hd[r2][j2];
                K[i2][j2]=acc;
            }
        double V[3][3]={{1,0,0},{0,1,0},{0,0,1}};
        const int PQ[3][2]={{0,1},{0,2},{1,2}};
        for (int sweep=0; sweep<30; ++sweep){
            double off = fabs(K[0][1])+fabs(K[0][2])+fabs(K[1][2]);
            if (off < 1e-26) break;
            for (int pi=0; pi<3; ++pi){
                int p = PQ[pi][0], q = PQ[pi][1];
                double apq = K[p][q];
                if (fabs(apq) < 1e-300) continue;
                double tau = (K[q][q]-K[p][p])/(2.0*apq);
                double tt  = (tau>=0.0?1.0:-1.0)/(fabs(tau)+sqrt(1.0+tau*tau));
                double c   = 1.0/sqrt(1.0+tt*tt);
                double s   = tt*c;
                double Kpp=K[p][p], Kqq=K[q][q];
                K[p][p] = Kpp - tt*apq;
                K[q][q] = Kqq + tt*apq;
                K[p][q] = 0.0; K[q][p] = 0.0;
                int r2 = 3-p-q;
                double Krp=K[r2][p], Krq=K[r2][q];
                K[r2][p] = c*Krp - s*Krq; K[p][r2]=K[r2][p];
                K[r2][q] = s*Krp + c*Krq; K[q][r2]=K[r2][q];
                for (int rr=0; rr<3; ++rr){
                    double vp=V[rr][p], vq=V[rr][q];
                    V[rr][p] = c*vp - s*vq;
                    V[rr][q] = s*vp + c*vq;
                }
            }
        }
        double lam[3]={K[0][0],K[1][1],K[2][2]};
        int o0=0,o1=1,o2=2,tmp;
        if (lam[o0]<lam[o1]){tmp=o0;o0=o1;o1=tmp;}
        if (lam[o0]<lam[o2]){tmp=o0;o0=o2;o2=tmp;}
        if (lam[o1]<lam[o2]){tmp=o1;o1=o2;o2=tmp;}
        int ord[3]={o0,o1,o2};
        double Vs[3][3], U[3][3];
        for (int k=0;k<3;k++)
            for (int r2=0;r2<3;r2++) Vs[r2][k]=V[r2][ord[k]];
        for (int k=0;k<3;k++){
            double ux = Hd[0][0]*Vs[0][k] + Hd[0][1]*Vs[1][k] + Hd[0][2]*Vs[2][k];
            double uy = Hd[1][0]*Vs[0][k] + Hd[1][1]*Vs[1][k] + Hd[1][2]*Vs[2][k];
            double uz = Hd[2][0]*Vs[0][k] + Hd[2][1]*Vs[1][k] + Hd[2][2]*Vs[2][k];
            double n = sqrt(ux*ux+uy*uy+uz*uz);
            if (n > 1e-30){ U[0][k]=ux/n; U[1][k]=uy/n; U[2][k]=uz/n; }
            else {
                double cx = U[1][0]*U[2][1]-U[2][0]*U[1][1];
                double cy = U[2][0]*U[0][1]-U[0][0]*U[2][1];
                double cz = U[0][0]*U[1][1]-U[1][0]*U[0][1];
                U[0][k]=cx; U[1][k]=cy; U[2][k]=cz;
            }
        }
        double rm[3][3];
        for (int i2=0;i2<3;i2++)
            for (int j2=0;j2<3;j2++)
                rm[i2][j2] = Vs[i2][0]*U[j2][0] + Vs[i2][1]*U[j2][1] + Vs[i2][2]*U[j2][2];
        double det = rm[0][0]*(rm[1][1]*rm[2][2]-rm[1][2]*rm[2][1])
                   - rm[0][1]*(rm[1][0]*rm[2][2]-rm[1][2]*rm[2][0])
                   + rm[0][2]*(rm[1][0]*rm[2][1]-rm[1][1]*rm[2][0]);
        double R[3][3];
        for (int i2=0;i2<3;i2++)
            for (int j2=0;j2<3;j2++)
                R[i2][j2] = Vs[i2][0]*U[j2][0] + Vs[i2][1]*U[j2][1] + det*Vs[i2][2]*U[j2][2];
        double tv[3];
        for (int i2=0;i2<3;i2++)
            tv[i2] = -(R[i2][0]*sc[0]+R[i2][1]*sc[1]+R[i2][2]*sc[2]) + tc[i2];
        for (int i2=0;i2<3;i2++)
            for (int j2=0;j2<3;j2++)
                out[b*9 + i2*3 + j2] = (float)R[i2][j2];
        for (int i2=0;i2<3;i2++)
            out[144 + b*3 + i2] = (float)tv[i2];
    }
}

extern "C" void kernel_launch(void* const* d_in, const int* in_sizes, int n_in,
                              void* d_out, int out_size, void* d_ws, size_t ws_size,
                              hipStream_t stream) {
    const float* src_emb = (const float*)d_in[0];
    const float* tgt_emb = (const float*)d_in[1];
    const float* src     = (const float*)d_in[2];
    const float* tgt     = (const float*)d_in[3];
    const float* temp    = (const float*)d_in[4];
    float* out = (float*)d_out;
    float* S = out + 192;   // perm_norm region doubles as scores buffer

    hipLaunchKernelGGL(zero_v_kernel, dim3(64), dim3(256), 0, stream);
    hipLaunchKernelGGL(convert_split, dim3(16,8,16), dim3(256), 0, stream, src_emb, 0);
    hipLaunchKernelGGL(convert_split, dim3(16,8,16), dim3(256), 0, stream, tgt_emb, 1);
    hipLaunchKernelGGL(gemm_mfma, dim3(8,8,16), dim3(256), 0, stream, temp, S);
    for (int it=0; it<5; ++it){
        hipLaunchKernelGGL(row_lse, dim3(4096), dim3(256), 0, stream, S);
        hipLaunchKernelGGL(col_lse_partial, dim3(4,CHUNKS,16), dim3(256), 0, stream, S);
        hipLaunchKernelGGL(col_lse_combine, dim3(64), dim3(256), 0, stream);
    }
    hipLaunchKernelGGL(finalize_rows, dim3(4096), dim3(256), 0, stream, S, tgt);
    hipLaunchKernelGGL(procrustes, dim3(16), dim3(256), 0, stream, src, out);
}

// Round 4
// 366.097 us; speedup vs baseline: 1.3434x; 1.1146x over previous
//
#include <hip/hip_runtime.h>
#include <math.h>

#define BB 16
#define NN 1024
#define MM 1024
#define DKK 512
#define RBLK 16                  // rows per sink_iter block
#define NRB  (NN/RBLK)           // 64 row-blocks per batch

typedef short short8 __attribute__((ext_vector_type(8)));
typedef float f32x4 __attribute__((ext_vector_type(4)));

// scratch as device globals (fully rewritten every call)
__device__ float g_u[BB*NN];
__device__ float g_v[BB*MM];
__device__ float g_w[BB*NN];
__device__ float g_wt[BB*3*NN];
__device__ float g_pm[BB*NRB*MM];   // col-lse partial max
__device__ float g_ps[BB*NRB*MM];   // col-lse partial sum
// split-bf16 operands, [B][N][DK] k-contiguous; 16B-aligned for uint4 access
__device__ __attribute__((aligned(16))) unsigned short gAh[BB*NN*DKK];
__device__ __attribute__((aligned(16))) unsigned short gAl[BB*NN*DKK];
__device__ __attribute__((aligned(16))) unsigned short gBh[BB*MM*DKK];
__device__ __attribute__((aligned(16))) unsigned short gBl[BB*MM*DKK];

__global__ __launch_bounds__(256) void zero_v_kernel() {
    int i = blockIdx.x*256 + threadIdx.x;
    if (i < BB*MM) g_v[i] = 0.0f;
}

__device__ __forceinline__ unsigned int bf16_rne(float x){
    unsigned int u = __float_as_uint(x);
    return (u + 0x7fffu + ((u>>16)&1u)) >> 16;
}

// X [16][512][1024] fp32 -> (which? gB : gA) hi/lo [16][1024][512] bf16, transposed.
// __device__ globals must not be passed as kernel args from host (shadow addr).
__global__ __launch_bounds__(256) void convert_split(const float* __restrict__ X,
                                                     int which) {
    unsigned short* Hh = which ? gBh : gAh;
    unsigned short* Hl = which ? gBl : gAl;
    int b  = blockIdx.z;
    int d0 = blockIdx.y * 64;
    int i0 = blockIdx.x * 64;
    __shared__ float T[64*65];
    const float* Xb = X + ((size_t)b*DKK + d0)*NN + i0;
    int t = threadIdx.x;
#pragma unroll
    for (int it=0; it<4; ++it){
        int lin = t + 256*it;
        int d = lin >> 4;
        int i4 = lin & 15;
        float4 v = *(const float4*)(Xb + (size_t)d*NN + i4*4);
        T[(i4*4+0)*65 + d] = v.x;
        T[(i4*4+1)*65 + d] = v.y;
        T[(i4*4+2)*65 + d] = v.z;
        T[(i4*4+3)*65 + d] = v.w;
    }
    __syncthreads();
    size_t obase = ((size_t)b*NN + i0)*DKK + d0;
#pragma unroll
    for (int it=0; it<2; ++it){
        int c = t + 256*it;
        int i = c >> 3;
        int p = c & 7;
        unsigned int hw[4], lw[4];
#pragma unroll
        for (int j=0;j<4;j++){
            float x0 = T[i*65 + p*8 + 2*j];
            float x1 = T[i*65 + p*8 + 2*j+1];
            unsigned int h0 = bf16_rne(x0);
            unsigned int h1 = bf16_rne(x1);
            float hf0 = __uint_as_float(h0<<16);
            float hf1 = __uint_as_float(h1<<16);
            unsigned int l0 = bf16_rne(x0 - hf0);
            unsigned int l1 = bf16_rne(x1 - hf1);
            hw[j] = h0 | (h1<<16);
            lw[j] = l0 | (l1<<16);
        }
        size_t eo = obase + (size_t)i*DKK + p*8;
        uint4 hv; hv.x=hw[0]; hv.y=hw[1]; hv.z=hw[2]; hv.w=hw[3];
        uint4 lv; lv.x=lw[0]; lv.y=lw[1]; lv.z=lw[2]; lv.w=lw[3];
        *(uint4*)(Hh + eo) = hv;
        *(uint4*)(Hl + eo) = lv;
    }
}

// C[b][i][j] = (sum_d A[d][i]*B[d][j]) / (sqrt(512)*temp[b]) via split-bf16 MFMA.
// 1-D grid, XCD-aware decode: XCD id%8 owns batches {2*xcd, 2*xcd+1} only,
// so per-XCD fetch = 8.4 MB (fits L2-ish) and no cross-XCD operand duplication.
__global__ __launch_bounds__(256) void gemm_mfma(const float* __restrict__ temp,
                                                 float* __restrict__ C) {
    int id   = blockIdx.x;
    int xcd  = id & 7;
    int slot = id >> 3;            // 0..127
    int b    = xcd*2 + (slot >> 6);
    int sub  = slot & 63;
    int i0   = (sub >> 3) << 7;
    int j0   = (sub & 7) << 7;
    __shared__ __attribute__((aligned(16))) char lds[40960];
    int t = threadIdx.x;
    int lane = t & 63, w = t >> 6;
    int wr = w >> 1, wc = w & 1;
    const size_t eb = (size_t)b * NN * DKK;
    const uint4* pAh = (const uint4*)(gAh + eb);
    const uint4* pAl = (const uint4*)(gAl + eb);
    const uint4* pBh = (const uint4*)(gBh + eb);
    const uint4* pBl = (const uint4*)(gBl + eb);
    int rr = t >> 2, pp = t & 3;

    f32x4 acc[16];
#pragma unroll
    for (int q=0;q<16;q++) acc[q] = (f32x4){0.f,0.f,0.f,0.f};

    uint4 ra0, ra1, la0, la1, rb0, rb1, lb0, lb1;
    auto loadk = [&](int k0){
        int kq = k0 >> 3;
        ra0 = pAh[(size_t)(i0+rr)*64 + kq + pp];
        ra1 = pAh[(size_t)(i0+rr+64)*64 + kq + pp];
        la0 = pAl[(size_t)(i0+rr)*64 + kq + pp];
        la1 = pAl[(size_t)(i0+rr+64)*64 + kq + pp];
        rb0 = pBh[(size_t)(j0+rr)*64 + kq + pp];
        rb1 = pBh[(size_t)(j0+rr+64)*64 + kq + pp];
        lb0 = pBl[(size_t)(j0+rr)*64 + kq + pp];
        lb1 = pBl[(size_t)(j0+rr+64)*64 + kq + pp];
    };
    loadk(0);

    const char* fa = lds + (wr*64 + (lane&15))*80 + (lane>>4)*16;
    const char* fb = lds + 20480 + (wc*64 + (lane&15))*80 + (lane>>4)*16;
    char* wbase = lds + rr*80 + pp*16;

    for (int ks=0; ks<16; ++ks){
        __syncthreads();
        *(uint4*)(wbase + 0)     = ra0;
        *(uint4*)(wbase + 5120)  = ra1;
        *(uint4*)(wbase + 10240) = la0;
        *(uint4*)(wbase + 15360) = la1;
        *(uint4*)(wbase + 20480) = rb0;
        *(uint4*)(wbase + 25600) = rb1;
        *(uint4*)(wbase + 30720) = lb0;
        *(uint4*)(wbase + 35840) = lb1;
        __syncthreads();
        if (ks+1 < 16) loadk((ks+1)*32);

        short8 ah[4], al[4];
#pragma unroll
        for (int mf=0;mf<4;mf++){
            ah[mf] = *(const short8*)(fa + mf*1280);
            al[mf] = *(const short8*)(fa + 10240 + mf*1280);
        }
#pragma unroll
        for (int nf=0;nf<4;nf++){
            short8 bh = *(const short8*)(fb + nf*1280);
            short8 bl = *(const short8*)(fb + 10240 + nf*1280);
#pragma unroll
            for (int mf=0;mf<4;mf++){
                acc[mf*4+nf] = __builtin_amdgcn_mfma_f32_16x16x32_bf16(ah[mf], bh, acc[mf*4+nf], 0,0,0);
                acc[mf*4+nf] = __builtin_amdgcn_mfma_f32_16x16x32_bf16(ah[mf], bl, acc[mf*4+nf], 0,0,0);
                acc[mf*4+nf] = __builtin_amdgcn_mfma_f32_16x16x32_bf16(al[mf], bh, acc[mf*4+nf], 0,0,0);
            }
        }
    }

    float scale = 1.0f/(22.62741699796952f * temp[b]);
    float* Cb = C + ((size_t)b<<20);
    int r0c = i0 + wr*64 + ((lane>>4)<<2);
    int c0c = j0 + wc*64 + (lane&15);
#pragma unroll
    for (int mf=0;mf<4;mf++){
#pragma unroll
        for (int r2=0;r2<4;r2++){
            float* rowp = Cb + (size_t)(r0c + mf*16 + r2)*MM + c0c;
#pragma unroll
            for (int nf=0;nf<4;nf++)
                rowp[nf*16] = acc[mf*4+nf][r2]*scale;
        }
    }
}

// One fused Sinkhorn iteration: block = 16 rows of one batch, tile in LDS.
// Loads (a - v) once; row pass -> u; col partials of (a-u) via +v_j at write.
__global__ __launch_bounds__(256) void sink_iter(const float* __restrict__ S) {
    int b   = blockIdx.y;
    int rb  = blockIdx.x;
    int row0 = rb*RBLK;
    int t = threadIdx.x;
    __shared__ float Ls[RBLK*1028];   // padded rows: bank-spread for col reads
    __shared__ float v_l[1024];
    __shared__ float u_l[RBLK];

    // v for this batch; keep a reg copy for the load-subtract
    float4 v4 = *(const float4*)(g_v + (b<<10) + t*4);
    *(float4*)(v_l + t*4) = v4;

    const float* Sb = S + ((size_t)b*NN + row0)*MM;
#pragma unroll
    for (int rr=0; rr<RBLK; ++rr){
        float4 s4 = *(const float4*)(Sb + (size_t)rr*MM + t*4);
        s4.x -= v4.x; s4.y -= v4.y; s4.z -= v4.z; s4.w -= v4.w;
        *(float4*)(&Ls[rr*1028 + t*4]) = s4;
    }
    __syncthreads();

    // row pass: thread t -> row r = t>>4, lane-chunk c = t&15, elems j = c+16k
    {
        int r = t >> 4, c = t & 15;
        const float* Lr = &Ls[r*1028 + c];
        float m = -INFINITY;
#pragma unroll
        for (int k=0;k<64;k++) m = fmaxf(m, Lr[16*k]);
#pragma unroll
        for (int off=1; off<16; off<<=1) m = fmaxf(m, __shfl_xor(m, off));
        m = fmaxf(m, 0.0f);           // slack col
        float s = 0.0f;
#pragma unroll
        for (int k=0;k<64;k++) s += __expf(Lr[16*k] - m);
#pragma unroll
        for (int off=1; off<16; off<<=1) s += __shfl_xor(s, off);
        s += __expf(-m);              // slack col
        float u = m + __logf(s);
        if (c==0){ u_l[r] = u; g_u[b*NN + row0 + r] = u; }
    }
    __syncthreads();

    // col pass: thread t -> cols j = t + 256q, over the 16 rows
    float mm[4], ss[4];
#pragma unroll
    for (int q=0;q<4;q++){ mm[q]=-INFINITY; ss[q]=0.f; }
#pragma unroll
    for (int r=0;r<RBLK;++r){
        float ur = u_l[r];
        const float* Lr = &Ls[r*1028];
#pragma unroll
        for (int q=0;q<4;q++)
            mm[q] = fmaxf(mm[q], Lr[t + 256*q] - ur);
    }
#pragma unroll
    for (int r=0;r<RBLK;++r){
        float ur = u_l[r];
        const float* Lr = &Ls[r*1028];
#pragma unroll
        for (int q=0;q<4;q++)
            ss[q] += __expf(Lr[t + 256*q] - ur - mm[q]);
    }
    size_t pbase = ((size_t)(b*NRB + rb) << 10) + t;
#pragma unroll
    for (int q=0;q<4;q++){
        g_pm[pbase + 256*q] = mm[q] + v_l[t + 256*q];   // restore: partial of (a-u)
        g_ps[pbase + 256*q] = ss[q];
    }
}

__global__ __launch_bounds__(256) void col_lse_combine() {
    int idx = blockIdx.x*256 + threadIdx.x;    // 16384 columns
    int b = idx >> 10; int j = idx & (MM-1);
    float m = -INFINITY, s = 0.0f;
    size_t base = ((size_t)(b*NRB) << 10) + j;
    for (int c=0;c<NRB;c++){
        float om = g_pm[base + ((size_t)c<<10)];
        float os = g_ps[base + ((size_t)c<<10)];
        float nm = fmaxf(m, om);
        s = s*__expf(m-nm) + os*__expf(om-nm);
        m = nm;
    }
    float nm = fmaxf(m, 0.0f);    // slack row
    s = s*__expf(m-nm) + __expf(-nm);
    g_v[idx] = nm + __logf(s);
}

__global__ __launch_bounds__(256) void finalize_rows(float* __restrict__ S,
                                                     const float* __restrict__ tgt) {
    int row  = blockIdx.x*4 + (threadIdx.x>>6);
    int lane = threadIdx.x & 63;
    int b = row >> 10;
    int i = row & (NN-1);
    float ui = g_u[row];
    float4* srow = (float4*)(S + (size_t)row*MM);
    const float4* vb = (const float4*)(g_v + (b<<10));
    const float4* t0 = (const float4*)(tgt + (size_t)b*3*MM);
    const float4* t1 = (const float4*)(tgt + (size_t)b*3*MM + MM);
    const float4* t2 = (const float4*)(tgt + (size_t)b*3*MM + 2*MM);
    float p[16];
    float rs=0.f, a0=0.f, a1=0.f, a2=0.f;
#pragma unroll
    for (int k=0;k<4;k++){
        float4 s4 = srow[lane + 64*k];
        float4 v4 = vb[lane + 64*k];
        p[4*k+0] = __expf(s4.x - ui - v4.x);
        p[4*k+1] = __expf(s4.y - ui - v4.y);
        p[4*k+2] = __expf(s4.z - ui - v4.z);
        p[4*k+3] = __expf(s4.w - ui - v4.w);
        rs += p[4*k+0]+p[4*k+1]+p[4*k+2]+p[4*k+3];
        float4 w0 = t0[lane + 64*k];
        float4 w1 = t1[lane + 64*k];
        float4 w2 = t2[lane + 64*k];
        a0 += p[4*k+0]*w0.x + p[4*k+1]*w0.y + p[4*k+2]*w0.z + p[4*k+3]*w0.w;
        a1 += p[4*k+0]*w1.x + p[4*k+1]*w1.y + p[4*k+2]*w1.z + p[4*k+3]*w1.w;
        a2 += p[4*k+0]*w2.x + p[4*k+1]*w2.y + p[4*k+2]*w2.z + p[4*k+3]*w2.w;
    }
    for (int off=32; off; off>>=1){
        rs += __shfl_xor(rs, off);
        a0 += __shfl_xor(a0, off);
        a1 += __shfl_xor(a1, off);
        a2 += __shfl_xor(a2, off);
    }
    float inv = 1.0f/(rs + 1e-8f);
#pragma unroll
    for (int k=0;k<4;k++){
        srow[lane + 64*k] = make_float4(p[4*k+0]*inv, p[4*k+1]*inv, p[4*k+2]*inv, p[4*k+3]*inv);
    }
    if (lane==0){
        g_w[row] = rs;
        g_wt[(b*3+0)*NN + i] = a0*inv;
        g_wt[(b*3+1)*NN + i] = a1*inv;
        g_wt[(b*3+2)*NN + i] = a2*inv;
    }
}

__global__ __launch_bounds__(256) void procrustes(const float* __restrict__ src,
                                                  float* __restrict__ out) {
    int b = blockIdx.x;
    int t = threadIdx.x;
    __shared__ float red[256];
    auto bsum = [&](float v)->float{
        red[t]=v; __syncthreads();
        for (int o=128;o>0;o>>=1){ if(t<o) red[t]+=red[t+o]; __syncthreads(); }
        float r=red[0]; __syncthreads(); return r;
    };
    const float* wrow = g_w + b*NN;
    float pw=0.f;
    for (int i=t;i<NN;i+=256) pw += wrow[i];
    float W = bsum(pw);
    float winv = 1.0f/(W + 1e-8f);
    const float* sb  = src  + (size_t)b*3*NN;
    const float* wtb = g_wt + (size_t)b*3*NN;
    float sc[3], tc[3];
    for (int c=0;c<3;c++){
        float p1=0.f,p2=0.f;
        for (int i=t;i<NN;i+=256){
            float wn = wrow[i]*winv;
            p1 += sb[c*NN+i]*wn;
            p2 += wtb[c*NN+i]*wn;
        }
        sc[c]=bsum(p1);
        tc[c]=bsum(p2);
    }
    float H[9];
    for (int c=0;c<3;c++)
        for (int d=0;d<3;d++){
            float p=0.f;
            for (int i=t;i<NN;i+=256){
                float wn = wrow[i]*winv;
                p += (sb[c*NN+i]-sc[c]) * ((wtb[d*NN+i]-tc[d])*wn);
            }
            H[c*3+d]=bsum(p);
        }
    if (t==0){
        double Hd[3][3];
        for (int r2=0;r2<3;r2++) for (int c2=0;c2<3;c2++) Hd[r2][c2]=H[r2*3+c2];
        double K[3][3];
        for (int i2=0;i2<3;i2++)
            for (int j2=0;j2<3;j2++){
                double acc=0;
                for (int r2=0;r2<3;r2++) acc += Hd[r2][i2]*Hd[r2][j2];
                K[i2][j2]=acc;
            }
        double V[3][3]={{1,0,0},{0,1,0},{0,0,1}};
        const int PQ[3][2]={{0,1},{0,2},{1,2}};
        for (int sweep=0; sweep<30; ++sweep){
            double off = fabs(K[0][1])+fabs(K[0][2])+fabs(K[1][2]);
            if (off < 1e-26) break;
            for (int pi=0; pi<3; ++pi){
                int p = PQ[pi][0], q = PQ[pi][1];
                double apq = K[p][q];
                if (fabs(apq) < 1e-300) continue;
                double tau = (K[q][q]-K[p][p])/(2.0*apq);
                double tt  = (tau>=0.0?1.0:-1.0)/(fabs(tau)+sqrt(1.0+tau*tau));
                double c   = 1.0/sqrt(1.0+tt*tt);
                double s   = tt*c;
                double Kpp=K[p][p], Kqq=K[q][q];
                K[p][p] = Kpp - tt*apq;
                K[q][q] = Kqq + tt*apq;
                K[p][q] = 0.0; K[q][p] = 0.0;
                int r2 = 3-p-q;
                double Krp=K[r2][p], Krq=K[r2][q];
                K[r2][p] = c*Krp - s*Krq; K[p][r2]=K[r2][p];
                K[r2][q] = s*Krp + c*Krq; K[q][r2]=K[r2][q];
                for (int rr=0; rr<3; ++rr){
                    double vp=V[rr][p], vq=V[rr][q];
                    V[rr][p] = c*vp - s*vq;
                    V[rr][q] = s*vp + c*vq;
                }
            }
        }
        double lam[3]={K[0][0],K[1][1],K[2][2]};
        int o0=0,o1=1,o2=2,tmp;
        if (lam[o0]<lam[o1]){tmp=o0;o0=o1;o1=tmp;}
        if (lam[o0]<lam[o2]){tmp=o0;o0=o2;o2=tmp;}
        if (lam[o1]<lam[o2]){tmp=o1;o1=o2;o2=tmp;}
        int ord[3]={o0,o1,o2};
        double Vs[3][3], U[3][3];
        for (int k=0;k<3;k++)
            for (int r2=0;r2<3;r2++) Vs[r2][k]=V[r2][ord[k]];
        for (int k=0;k<3;k++){
            double ux = Hd[0][0]*Vs[0][k] + Hd[0][1]*Vs[1][k] + Hd[0][2]*Vs[2][k];
            double uy = Hd[1][0]*Vs[0][k] + Hd[1][1]*Vs[1][k] + Hd[1][2]*Vs[2][k];
            double uz = Hd[2][0]*Vs[0][k] + Hd[2][1]*Vs[1][k] + Hd[2][2]*Vs[2][k];
            double n = sqrt(ux*ux+uy*uy+uz*uz);
            if (n > 1e-30){ U[0][k]=ux/n; U[1][k]=uy/n; U[2][k]=uz/n; }
            else {
                double cx = U[1][0]*U[2][1]-U[2][0]*U[1][1];
                double cy = U[2][0]*U[0][1]-U[0][0]*U[2][1];
                double cz = U[0][0]*U[1][1]-U[1][0]*U[0][1];
                U[0][k]=cx; U[1][k]=cy; U[2][k]=cz;
            }
        }
        double rm[3][3];
        for (int i2=0;i2<3;i2++)
            for (int j2=0;j2<3;j2++)
                rm[i2][j2] = Vs[i2][0]*U[j2][0] + Vs[i2][1]*U[j2][1] + Vs[i2][2]*U[j2][2];
        double det = rm[0][0]*(rm[1][1]*rm[2][2]-rm[1][2]*rm[2][1])
                   - rm[0][1]*(rm[1][0]*rm[2][2]-rm[1][2]*rm[2][0])
                   + rm[0][2]*(rm[1][0]*rm[2][1]-rm[1][1]*rm[2][0]);
        double R[3][3];
        for (int i2=0;i2<3;i2++)
            for (int j2=0;j2<3;j2++)
                R[i2][j2] = Vs[i2][0]*U[j2][0] + Vs[i2][1]*U[j2][1] + det*Vs[i2][2]*U[j2][2];
        double tv[3];
        for (int i2=0;i2<3;i2++)
            tv[i2] = -(R[i2][0]*sc[0]+R[i2][1]*sc[1]+R[i2][2]*sc[2]) + tc[i2];
        for (int i2=0;i2<3;i2++)
            for (int j2=0;j2<3;j2++)
                out[b*9 + i2*3 + j2] = (float)R[i2][j2];
        for (int i2=0;i2<3;i2++)
            out[144 + b*3 + i2] = (float)tv[i2];
    }
}

extern "C" void kernel_launch(void* const* d_in, const int* in_sizes, int n_in,
                              void* d_out, int out_size, void* d_ws, size_t ws_size,
                              hipStream_t stream) {
    const float* src_emb = (const float*)d_in[0];
    const float* tgt_emb = (const float*)d_in[1];
    const float* src     = (const float*)d_in[2];
    const float* tgt     = (const float*)d_in[3];
    const float* temp    = (const float*)d_in[4];
    float* out = (float*)d_out;
    float* S = out + 192;   // perm_norm region doubles as scores buffer

    hipLaunchKernelGGL(zero_v_kernel, dim3(64), dim3(256), 0, stream);
    hipLaunchKernelGGL(convert_split, dim3(16,8,16), dim3(256), 0, stream, src_emb, 0);
    hipLaunchKernelGGL(convert_split, dim3(16,8,16), dim3(256), 0, stream, tgt_emb, 1);
    hipLaunchKernelGGL(gemm_mfma, dim3(1024), dim3(256), 0, stream, temp, S);
    for (int it=0; it<5; ++it){
        hipLaunchKernelGGL(sink_iter, dim3(NRB,BB), dim3(256), 0, stream, S);
        hipLaunchKernelGGL(col_lse_combine, dim3(64), dim3(256), 0, stream);
    }
    hipLaunchKernelGGL(finalize_rows, dim3(4096), dim3(256), 0, stream, S, tgt);
    hipLaunchKernelGGL(procrustes, dim3(16), dim3(256), 0, stream, src, out);
}

// Round 5
// 360.082 us; speedup vs baseline: 1.3659x; 1.0167x over previous
//
#include <hip/hip_runtime.h>
#include <math.h>

#define BB 16
#define NN 1024
#define MM 1024
#define DKK 512
#define RBLK 16                  // rows per sink_iter block
#define NRB  (NN/RBLK)           // 64 row-blocks per batch

typedef short short8 __attribute__((ext_vector_type(8)));
typedef float f32x4 __attribute__((ext_vector_type(4)));

// scratch as device globals (fully rewritten every call)
__device__ float g_u[BB*NN];
__device__ float g_v[BB*MM];
__device__ float g_w[BB*NN];
__device__ float g_wt[BB*3*NN];
__device__ float g_pm[BB*NRB*MM];   // col-lse partial max
__device__ float g_ps[BB*NRB*MM];   // col-lse partial sum
// split-bf16 operands, [B][N][DK] k-contiguous, chunk-swizzled (see convert_split)
__device__ __attribute__((aligned(16))) unsigned short gAh[BB*NN*DKK];
__device__ __attribute__((aligned(16))) unsigned short gAl[BB*NN*DKK];
__device__ __attribute__((aligned(16))) unsigned short gBh[BB*MM*DKK];
__device__ __attribute__((aligned(16))) unsigned short gBl[BB*MM*DKK];

__global__ __launch_bounds__(256) void zero_v_kernel() {
    int i = blockIdx.x*256 + threadIdx.x;
    if (i < BB*MM) g_v[i] = 0.0f;
}

__device__ __forceinline__ unsigned int bf16_rne(float x){
    unsigned int u = __float_as_uint(x);
    return (u + 0x7fffu + ((u>>16)&1u)) >> 16;
}

// async global->LDS DMA, 16B per lane; LDS dest = wave-uniform base + lane*16
__device__ __forceinline__ void gl_lds(const void* g, void* l){
    __builtin_amdgcn_global_load_lds(
        (const __attribute__((address_space(1))) unsigned int*)g,
        (__attribute__((address_space(3))) unsigned int*)l, 16, 0, 0);
}

// X [16][512][1024] fp32 -> hi/lo bf16 [16][1024][512], transposed, with the
// 16B-chunk swizzle baked in: semantic chunk p (within a row) is stored at
// slot (p&4)|((p + (row>>1))&3) so gemm's lane-contiguous global_load_lds
// staging yields conflict-free LDS fragment reads.
// z: 0..31 -> which = z>>4 (0=A,1=B), b = z&15.
__global__ __launch_bounds__(256) void convert_split(const float* __restrict__ A,
                                                     const float* __restrict__ Bm) {
    int z = blockIdx.z;
    int which = z >> 4;
    int b = z & 15;
    const float* X = which ? Bm : A;
    unsigned short* Hh = which ? gBh : gAh;
    unsigned short* Hl = which ? gBl : gAl;
    int d0 = blockIdx.y * 64;
    int i0 = blockIdx.x * 64;
    __shared__ float T[64*65];
    const float* Xb = X + ((size_t)b*DKK + d0)*NN + i0;
    int t = threadIdx.x;
#pragma unroll
    for (int it=0; it<4; ++it){
        int lin = t + 256*it;
        int d = lin >> 4;
        int i4 = lin & 15;
        float4 v = *(const float4*)(Xb + (size_t)d*NN + i4*4);
        T[(i4*4+0)*65 + d] = v.x;
        T[(i4*4+1)*65 + d] = v.y;
        T[(i4*4+2)*65 + d] = v.z;
        T[(i4*4+3)*65 + d] = v.w;
    }
    __syncthreads();
    size_t obase = ((size_t)b*NN + i0)*DKK + d0;
#pragma unroll
    for (int it=0; it<2; ++it){
        int c = t + 256*it;
        int i = c >> 3;            // row 0..63 within i0 block
        int p = c & 7;             // semantic 16B chunk within this 64-d block
        unsigned int hw[4], lw[4];
#pragma unroll
        for (int j=0;j<4;j++){
            float x0 = T[i*65 + p*8 + 2*j];
            float x1 = T[i*65 + p*8 + 2*j+1];
            unsigned int h0 = bf16_rne(x0);
            unsigned int h1 = bf16_rne(x1);
            float hf0 = __uint_as_float(h0<<16);
            float hf1 = __uint_as_float(h1<<16);
            unsigned int l0 = bf16_rne(x0 - hf0);
            unsigned int l1 = bf16_rne(x1 - hf1);
            hw[j] = h0 | (h1<<16);
            lw[j] = l0 | (l1<<16);
        }
        int pw = (p & 4) | ((p + (i>>1)) & 3);   // swizzled slot
        size_t eo = obase + (size_t)i*DKK + pw*8;
        uint4 hv; hv.x=hw[0]; hv.y=hw[1]; hv.z=hw[2]; hv.w=hw[3];
        uint4 lv; lv.x=lw[0]; lv.y=lw[1]; lv.z=lw[2]; lv.w=lw[3];
        *(uint4*)(Hh + eo) = hv;
        *(uint4*)(Hl + eo) = lv;
    }
}

// C[b][i][j] = (sum_d A[d][i]*B[d][j]) / (sqrt(512)*temp[b]) via split-bf16 MFMA.
// XCD-aware 1-D grid; global_load_lds staging; LDS double-buffer, 1 barrier/iter;
// MFMA in 3 independent groups of 16 (hh, lh, hl) to avoid same-acc chains.
__global__ __launch_bounds__(256) void gemm_mfma(const float* __restrict__ temp,
                                                 float* __restrict__ C) {
    int id   = blockIdx.x;
    int xcd  = id & 7;
    int slot = id >> 3;
    int b    = xcd*2 + (slot >> 6);
    int sub  = slot & 63;
    int i0   = (sub >> 3) << 7;
    int j0   = (sub & 7) << 7;
    __shared__ __attribute__((aligned(16))) char lds[65536];  // 2 x 32KB buffers
    int t = threadIdx.x;
    int lane = t & 63, w = t >> 6;
    int wr = w >> 1, wc = w & 1;
    const size_t ebytes = (size_t)b * NN * DKK * 2;

    // staging sources: 8 instrs/wave/ks; idx = o*2+q; o: 0=Ah 1=Al 2=Bh 3=Bl
    const char* src[8];
    int dstoff[8];
    {
        int rql = lane >> 2, cl = lane & 3;
#pragma unroll
        for (int o=0;o<4;o++){
            const char* g = (o==0) ? (const char*)gAh : (o==1) ? (const char*)gAl
                           : (o==2) ? (const char*)gBh : (const char*)gBl;
            int t0 = (o<2) ? i0 : j0;
#pragma unroll
            for (int q=0;q<2;q++){
                int rloc = w*32 + q*16 + rql;
                src[o*2+q] = g + ebytes + (size_t)(t0 + rloc)*1024 + cl*16;
                dstoff[o*2+q] = o*8192 + (w*32 + q*16)*64;
            }
        }
    }

    f32x4 acc[16];
#pragma unroll
    for (int q=0;q<16;q++) acc[q] = (f32x4){0.f,0.f,0.f,0.f};

    // fragment read addresses (swizzle collapses to a per-thread constant slot)
    int fslot = ((lane>>4) + ((lane&15)>>1)) & 3;
    int arow = wr*64 + (lane&15);
    int brow = wc*64 + (lane&15);
    int faoff = arow*64 + fslot*16;            // Ah; Al at +8192
    int fboff = 16384 + brow*64 + fslot*16;    // Bh; Bl at +8192

    // prologue: stage ks=0 into buffer 0
#pragma unroll
    for (int idx=0;idx<8;idx++) gl_lds(src[idx], lds + dstoff[idx]);

    for (int ks=0; ks<16; ++ks){
        __syncthreads();   // drains vmcnt: buffer ks&1 ready; all waves done with prev buffer
        int cur = (ks & 1) * 32768;
        if (ks+1 < 16){
            int nxt = ((ks+1) & 1) * 32768;
#pragma unroll
            for (int idx=0;idx<8;idx++){
                src[idx] += 64;
                gl_lds(src[idx], lds + nxt + dstoff[idx]);
            }
        }
        const char* fa = lds + cur + faoff;
        const char* fb = lds + cur + fboff;

        short8 ah[4], bh[4];
#pragma unroll
        for (int mf=0;mf<4;mf++) ah[mf] = *(const short8*)(fa + mf*1024);
#pragma unroll
        for (int nf=0;nf<4;nf++) bh[nf] = *(const short8*)(fb + nf*1024);
#pragma unroll
        for (int nf=0;nf<4;nf++)
#pragma unroll
            for (int mf=0;mf<4;mf++)
                acc[mf*4+nf] = __builtin_amdgcn_mfma_f32_16x16x32_bf16(ah[mf], bh[nf], acc[mf*4+nf], 0,0,0);

        short8 al[4];
#pragma unroll
        for (int mf=0;mf<4;mf++) al[mf] = *(const short8*)(fa + 8192 + mf*1024);
#pragma unroll
        for (int nf=0;nf<4;nf++)
#pragma unroll
            for (int mf=0;mf<4;mf++)
                acc[mf*4+nf] = __builtin_amdgcn_mfma_f32_16x16x32_bf16(al[mf], bh[nf], acc[mf*4+nf], 0,0,0);

        short8 bl[4];
#pragma unroll
        for (int nf=0;nf<4;nf++) bl[nf] = *(const short8*)(fb + 8192 + nf*1024);
#pragma unroll
        for (int nf=0;nf<4;nf++)
#pragma unroll
            for (int mf=0;mf<4;mf++)
                acc[mf*4+nf] = __builtin_amdgcn_mfma_f32_16x16x32_bf16(ah[mf], bl[nf], acc[mf*4+nf], 0,0,0);
    }

    float scale = 1.0f/(22.62741699796952f * temp[b]);
    float* Cb = C + ((size_t)b<<20);
    int r0c = i0 + wr*64 + ((lane>>4)<<2);
    int c0c = j0 + wc*64 + (lane&15);
#pragma unroll
    for (int mf=0;mf<4;mf++){
#pragma unroll
        for (int r2=0;r2<4;r2++){
            float* rowp = Cb + (size_t)(r0c + mf*16 + r2)*MM + c0c;
#pragma unroll
            for (int nf=0;nf<4;nf++)
                rowp[nf*16] = acc[mf*4+nf][r2]*scale;
        }
    }
}

// One fused Sinkhorn iteration: block = 16 rows of one batch, tile in LDS.
__global__ __launch_bounds__(256) void sink_iter(const float* __restrict__ S) {
    int b   = blockIdx.y;
    int rb  = blockIdx.x;
    int row0 = rb*RBLK;
    int t = threadIdx.x;
    __shared__ float Ls[RBLK*1028];
    __shared__ float v_l[1024];
    __shared__ float u_l[RBLK];

    float4 v4 = *(const float4*)(g_v + (b<<10) + t*4);
    *(float4*)(v_l + t*4) = v4;

    const float* Sb = S + ((size_t)b*NN + row0)*MM;
#pragma unroll
    for (int rr=0; rr<RBLK; ++rr){
        float4 s4 = *(const float4*)(Sb + (size_t)rr*MM + t*4);
        s4.x -= v4.x; s4.y -= v4.y; s4.z -= v4.z; s4.w -= v4.w;
        *(float4*)(&Ls[rr*1028 + t*4]) = s4;
    }
    __syncthreads();

    {
        int r = t >> 4, c = t & 15;
        const float* Lr = &Ls[r*1028 + c];
        float m = -INFINITY;
#pragma unroll
        for (int k=0;k<64;k++) m = fmaxf(m, Lr[16*k]);
#pragma unroll
        for (int off=1; off<16; off<<=1) m = fmaxf(m, __shfl_xor(m, off));
        m = fmaxf(m, 0.0f);
        float s = 0.0f;
#pragma unroll
        for (int k=0;k<64;k++) s += __expf(Lr[16*k] - m);
#pragma unroll
        for (int off=1; off<16; off<<=1) s += __shfl_xor(s, off);
        s += __expf(-m);
        float u = m + __logf(s);
        if (c==0){ u_l[r] = u; g_u[b*NN + row0 + r] = u; }
    }
    __syncthreads();

    float mm[4], ss[4];
#pragma unroll
    for (int q=0;q<4;q++){ mm[q]=-INFINITY; ss[q]=0.f; }
#pragma unroll
    for (int r=0;r<RBLK;++r){
        float ur = u_l[r];
        const float* Lr = &Ls[r*1028];
#pragma unroll
        for (int q=0;q<4;q++)
            mm[q] = fmaxf(mm[q], Lr[t + 256*q] - ur);
    }
#pragma unroll
    for (int r=0;r<RBLK;++r){
        float ur = u_l[r];
        const float* Lr = &Ls[r*1028];
#pragma unroll
        for (int q=0;q<4;q++)
            ss[q] += __expf(Lr[t + 256*q] - ur - mm[q]);
    }
    size_t pbase = ((size_t)(b*NRB + rb) << 10) + t;
#pragma unroll
    for (int q=0;q<4;q++){
        g_pm[pbase + 256*q] = mm[q] + v_l[t + 256*q];
        g_ps[pbase + 256*q] = ss[q];
    }
}

__global__ __launch_bounds__(256) void col_lse_combine() {
    int idx = blockIdx.x*256 + threadIdx.x;
    int b = idx >> 10; int j = idx & (MM-1);
    float m = -INFINITY, s = 0.0f;
    size_t base = ((size_t)(b*NRB) << 10) + j;
    for (int c=0;c<NRB;c++){
        float om = g_pm[base + ((size_t)c<<10)];
        float os = g_ps[base + ((size_t)c<<10)];
        float nm = fmaxf(m, om);
        s = s*__expf(m-nm) + os*__expf(om-nm);
        m = nm;
    }
    float nm = fmaxf(m, 0.0f);
    s = s*__expf(m-nm) + __expf(-nm);
    g_v[idx] = nm + __logf(s);
}

__global__ __launch_bounds__(256) void finalize_rows(float* __restrict__ S,
                                                     const float* __restrict__ tgt) {
    int row  = blockIdx.x*4 + (threadIdx.x>>6);
    int lane = threadIdx.x & 63;
    int b = row >> 10;
    int i = row & (NN-1);
    float ui = g_u[row];
    float4* srow = (float4*)(S + (size_t)row*MM);
    const float4* vb = (const float4*)(g_v + (b<<10));
    const float4* t0 = (const float4*)(tgt + (size_t)b*3*MM);
    const float4* t1 = (const float4*)(tgt + (size_t)b*3*MM + MM);
    const float4* t2 = (const float4*)(tgt + (size_t)b*3*MM + 2*MM);
    float p[16];
    float rs=0.f, a0=0.f, a1=0.f, a2=0.f;
#pragma unroll
    for (int k=0;k<4;k++){
        float4 s4 = srow[lane + 64*k];
        float4 v4 = vb[lane + 64*k];
        p[4*k+0] = __expf(s4.x - ui - v4.x);
        p[4*k+1] = __expf(s4.y - ui - v4.y);
        p[4*k+2] = __expf(s4.z - ui - v4.z);
        p[4*k+3] = __expf(s4.w - ui - v4.w);
        rs += p[4*k+0]+p[4*k+1]+p[4*k+2]+p[4*k+3];
        float4 w0 = t0[lane + 64*k];
        float4 w1 = t1[lane + 64*k];
        float4 w2 = t2[lane + 64*k];
        a0 += p[4*k+0]*w0.x + p[4*k+1]*w0.y + p[4*k+2]*w0.z + p[4*k+3]*w0.w;
        a1 += p[4*k+0]*w1.x + p[4*k+1]*w1.y + p[4*k+2]*w1.z + p[4*k+3]*w1.w;
        a2 += p[4*k+0]*w2.x + p[4*k+1]*w2.y + p[4*k+2]*w2.z + p[4*k+3]*w2.w;
    }
    for (int off=32; off; off>>=1){
        rs += __shfl_xor(rs, off);
        a0 += __shfl_xor(a0, off);
        a1 += __shfl_xor(a1, off);
        a2 += __shfl_xor(a2, off);
    }
    float inv = 1.0f/(rs + 1e-8f);
#pragma unroll
    for (int k=0;k<4;k++){
        srow[lane + 64*k] = make_float4(p[4*k+0]*inv, p[4*k+1]*inv, p[4*k+2]*inv, p[4*k+3]*inv);
    }
    if (lane==0){
        g_w[row] = rs;
        g_wt[(b*3+0)*NN + i] = a0*inv;
        g_wt[(b*3+1)*NN + i] = a1*inv;
        g_wt[(b*3+2)*NN + i] = a2*inv;
    }
}

__global__ __launch_bounds__(256) void procrustes(const float* __restrict__ src,
                                                  float* __restrict__ out) {
    int b = blockIdx.x;
    int t = threadIdx.x;
    __shared__ float red[256];
    auto bsum = [&](float v)->float{
        red[t]=v; __syncthreads();
        for (int o=128;o>0;o>>=1){ if(t<o) red[t]+=red[t+o]; __syncthreads(); }
        float r=red[0]; __syncthreads(); return r;
    };
    const float* wrow = g_w + b*NN;
    float pw=0.f;
    for (int i=t;i<NN;i+=256) pw += wrow[i];
    float W = bsum(pw);
    float winv = 1.0f/(W + 1e-8f);
    const float* sb  = src  + (size_t)b*3*NN;
    const float* wtb = g_wt + (size_t)b*3*NN;
    float sc[3], tc[3];
    for (int c=0;c<3;c++){
        float p1=0.f,p2=0.f;
        for (int i=t;i<NN;i+=256){
            float wn = wrow[i]*winv;
            p1 += sb[c*NN+i]*wn;
            p2 += wtb[c*NN+i]*wn;
        }
        sc[c]=bsum(p1);
        tc[c]=bsum(p2);
    }
    float H[9];
    for (int c=0;c<3;c++)
        for (int d=0;d<3;d++){
            float p=0.f;
            for (int i=t;i<NN;i+=256){
                float wn = wrow[i]*winv;
                p += (sb[c*NN+i]-sc[c]) * ((wtb[d*NN+i]-tc[d])*wn);
            }
            H[c*3+d]=bsum(p);
        }
    if (t==0){
        double Hd[3][3];
        for (int r2=0;r2<3;r2++) for (int c2=0;c2<3;c2++) Hd[r2][c2]=H[r2*3+c2];
        double K[3][3];
        for (int i2=0;i2<3;i2++)
            for (int j2=0;j2<3;j2++){
                double acc=0;
                for (int r2=0;r2<3;r2++) acc += Hd[r2][i2]*Hd[r2][j2];
                K[i2][j2]=acc;
            }
        double V[3][3]={{1,0,0},{0,1,0},{0,0,1}};
        const int PQ[3][2]={{0,1},{0,2},{1,2}};
        for (int sweep=0; sweep<30; ++sweep){
            double off = fabs(K[0][1])+fabs(K[0][2])+fabs(K[1][2]);
            if (off < 1e-26) break;
            for (int pi=0; pi<3; ++pi){
                int p = PQ[pi][0], q = PQ[pi][1];
                double apq = K[p][q];
                if (fabs(apq) < 1e-300) continue;
                double tau = (K[q][q]-K[p][p])/(2.0*apq);
                double tt  = (tau>=0.0?1.0:-1.0)/(fabs(tau)+sqrt(1.0+tau*tau));
                double c   = 1.0/sqrt(1.0+tt*tt);
                double s   = tt*c;
                double Kpp=K[p][p], Kqq=K[q][q];
                K[p][p] = Kpp - tt*apq;
                K[q][q] = Kqq + tt*apq;
                K[p][q] = 0.0; K[q][p] = 0.0;
                int r2 = 3-p-q;
                double Krp=K[r2][p], Krq=K[r2][q];
                K[r2][p] = c*Krp - s*Krq; K[p][r2]=K[r2][p];
                K[r2][q] = s*Krp + c*Krq; K[q][r2]=K[r2][q];
                for (int rr=0; rr<3; ++rr){
                    double vp=V[rr][p], vq=V[rr][q];
                    V[rr][p] = c*vp - s*vq;
                    V[rr][q] = s*vp + c*vq;
                }
            }
        }
        double lam[3]={K[0][0],K[1][1],K[2][2]};
        int o0=0,o1=1,o2=2,tmp;
        if (lam[o0]<lam[o1]){tmp=o0;o0=o1;o1=tmp;}
        if (lam[o0]<lam[o2]){tmp=o0;o0=o2;o2=tmp;}
        if (lam[o1]<lam[o2]){tmp=o1;o1=o2;o2=tmp;}
        int ord[3]={o0,o1,o2};
        double Vs[3][3], U[3][3];
        for (int k=0;k<3;k++)
            for (int r2=0;r2<3;r2++) Vs[r2][k]=V[r2][ord[k]];
        for (int k=0;k<3;k++){
            double ux = Hd[0][0]*Vs[0][k] + Hd[0][1]*Vs[1][k] + Hd[0][2]*Vs[2][k];
            double uy = Hd[1][0]*Vs[0][k] + Hd[1][1]*Vs[1][k] + Hd[1][2]*Vs[2][k];
            double uz = Hd[2][0]*Vs[0][k] + Hd[2][1]*Vs[1][k] + Hd[2][2]*Vs[2][k];
            double n = sqrt(ux*ux+uy*uy+uz*uz);
            if (n > 1e-30){ U[0][k]=ux/n; U[1][k]=uy/n; U[2][k]=uz/n; }
            else {
                double cx = U[1][0]*U[2][1]-U[2][0]*U[1][1];
                double cy = U[2][0]*U[0][1]-U[0][0]*U[2][1];
                double cz = U[0][0]*U[1][1]-U[1][0]*U[0][1];
                U[0][k]=cx; U[1][k]=cy; U[2][k]=cz;
            }
        }
        double rm[3][3];
        for (int i2=0;i2<3;i2++)
            for (int j2=0;j2<3;j2++)
                rm[i2][j2] = Vs[i2][0]*U[j2][0] + Vs[i2][1]*U[j2][1] + Vs[i2][2]*U[j2][2];
        double det = rm[0][0]*(rm[1][1]*rm[2][2]-rm[1][2]*rm[2][1])
                   - rm[0][1]*(rm[1][0]*rm[2][2]-rm[1][2]*rm[2][0])
                   + rm[0][2]*(rm[1][0]*rm[2][1]-rm[1][1]*rm[2][0]);
        double R[3][3];
        for (int i2=0;i2<3;i2++)
            for (int j2=0;j2<3;j2++)
                R[i2][j2] = Vs[i2][0]*U[j2][0] + Vs[i2][1]*U[j2][1] + det*Vs[i2][2]*U[j2][2];
        double tv[3];
        for (int i2=0;i2<3;i2++)
            tv[i2] = -(R[i2][0]*sc[0]+R[i2][1]*sc[1]+R[i2][2]*sc[2]) + tc[i2];
        for (int i2=0;i2<3;i2++)
            for (int j2=0;j2<3;j2++)
                out[b*9 + i2*3 + j2] = (float)R[i2][j2];
        for (int i2=0;i2<3;i2++)
            out[144 + b*3 + i2] = (float)tv[i2];
    }
}

extern "C" void kernel_launch(void* const* d_in, const int* in_sizes, int n_in,
                              void* d_out, int out_size, void* d_ws, size_t ws_size,
                              hipStream_t stream) {
    const float* src_emb = (const float*)d_in[0];
    const float* tgt_emb = (const float*)d_in[1];
    const float* src     = (const float*)d_in[2];
    const float* tgt     = (const float*)d_in[3];
    const float* temp    = (const float*)d_in[4];
    float* out = (float*)d_out;
    float* S = out + 192;   // perm_norm region doubles as scores buffer

    hipLaunchKernelGGL(zero_v_kernel, dim3(64), dim3(256), 0, stream);
    hipLaunchKernelGGL(convert_split, dim3(16,8,32), dim3(256), 0, stream, src_emb, tgt_emb);
    hipLaunchKernelGGL(gemm_mfma, dim3(1024), dim3(256), 0, stream, temp, S);
    for (int it=0; it<5; ++it){
        hipLaunchKernelGGL(sink_iter, dim3(NRB,BB), dim3(256), 0, stream, S);
        hipLaunchKernelGGL(col_lse_combine, dim3(64), dim3(256), 0, stream);
    }
    hipLaunchKernelGGL(finalize_rows, dim3(4096), dim3(256), 0, stream, S, tgt);
    hipLaunchKernelGGL(procrustes, dim3(16), dim3(256), 0, stream, src, out);
}